// Round 6
// baseline (527.173 us; speedup 1.0000x reference)
//
#include <hip/hip_runtime.h>
#include <hip/hip_bf16.h>
#include <math.h>

#define NN 50000
#define EE 500000
#define DIN 384
#define HIDD 128
#define NHEAD 8
#define OUTD 16

typedef __attribute__((ext_vector_type(8))) __bf16 bf16x8;
typedef __attribute__((ext_vector_type(4))) float f32x4;

__device__ __forceinline__ ushort f2bf(float f) {
  union { float f; unsigned u; } v; v.f = f;
  unsigned r = v.u + 0x7fffu + ((v.u >> 16) & 1u);
  return (ushort)(r >> 16);
}
__device__ __forceinline__ float bflo(unsigned w) {
  union { unsigned u; float f; } v; v.u = w << 16; return v.f;
}
__device__ __forceinline__ float bfhi(unsigned w) {
  union { unsigned u; float f; } v; v.u = w & 0xffff0000u; return v.f;
}

// ---------------- CSR build ----------------
__global__ void zero_ints(int* p, int n) {
  int i = blockIdx.x * blockDim.x + threadIdx.x;
  if (i < n) p[i] = 0;
}

__global__ void hist_kernel(const int* __restrict__ dst, int* __restrict__ counts, int e) {
  int i = blockIdx.x * blockDim.x + threadIdx.x;
  if (i < e) atomicAdd(&counts[dst[i]], 1);
}

#define SCAN_BS 256
#define SCAN_NBLK ((NN + SCAN_BS - 1) / SCAN_BS)  // 196

__global__ __launch_bounds__(256) void partial_sums(const int* __restrict__ counts,
                                                    int* __restrict__ bsum, int n) {
  __shared__ int red[256];
  int i = blockIdx.x * 256 + threadIdx.x;
  red[threadIdx.x] = (i < n) ? counts[i] : 0;
  __syncthreads();
  #pragma unroll
  for (int off = 128; off; off >>= 1) {
    if (threadIdx.x < off) red[threadIdx.x] += red[threadIdx.x + off];
    __syncthreads();
  }
  if (threadIdx.x == 0) bsum[blockIdx.x] = red[0];
}

__global__ __launch_bounds__(256) void scan_bsums(const int* __restrict__ bsum,
                                                  int* __restrict__ boff, int nb) {
  __shared__ int buf[256];
  int t = threadIdx.x;
  int v = (t < nb) ? bsum[t] : 0;
  buf[t] = v;
  __syncthreads();
  #pragma unroll
  for (int off = 1; off < 256; off <<= 1) {
    int u = (t >= off) ? buf[t - off] : 0;
    __syncthreads();
    buf[t] += u;
    __syncthreads();
  }
  if (t < nb) boff[t] = buf[t] - v;
}

__global__ __launch_bounds__(256) void final_scan(const int* __restrict__ counts,
                                                  const int* __restrict__ boff,
                                                  int* __restrict__ rowptr,
                                                  int* __restrict__ woff, int n) {
  __shared__ int buf[256];
  int i = blockIdx.x * 256 + threadIdx.x;
  int t = threadIdx.x;
  int v = (i < n) ? counts[i] : 0;
  buf[t] = v;
  __syncthreads();
  #pragma unroll
  for (int off = 1; off < 256; off <<= 1) {
    int u = (t >= off) ? buf[t - off] : 0;
    __syncthreads();
    buf[t] += u;
    __syncthreads();
  }
  int excl = boff[blockIdx.x] + buf[t] - v;
  if (i < n) { rowptr[i] = excl; woff[i] = excl; }
  if (i == n - 1) rowptr[n] = excl + v;
}

__global__ void scatter_kernel(const int* __restrict__ src, const int* __restrict__ dst,
                               int* __restrict__ woff, int* __restrict__ col, int e) {
  int i = blockIdx.x * blockDim.x + threadIdx.x;
  if (i < e) {
    int p = atomicAdd(&woff[dst[i]], 1);
    col[p] = src[i];
  }
}

// ---------------- weight prep ----------------
// wt layout (ushort):
//  [0..49151]          proj_wt [n=128][k=384]
//  [49152 + l*16384]   lin_wt_l [n=128][k=128]   (l=0..2)
//  [98304..106495]     cls_w1t [n=64][k=128]
//  [106496..107519]    cls_w2t [n=16][k=64]
__global__ void prep_weights(const float* __restrict__ proj_w,
                             const float* __restrict__ lin_w,
                             const float* __restrict__ cls_w1,
                             const float* __restrict__ cls_w2,
                             ushort* __restrict__ wt) {
  int i = blockIdx.x * blockDim.x + threadIdx.x;
  if (i < 49152) {
    int k = i >> 7, n = i & 127;
    wt[n * 384 + k] = f2bf(proj_w[i]);
  } else if (i < 98304) {
    int j = i - 49152;
    int l = j >> 14, rem = j & 16383;
    int k = rem >> 7, n = rem & 127;
    wt[49152 + l * 16384 + n * 128 + k] = f2bf(lin_w[j]);
  } else if (i < 106496) {
    int j = i - 98304;
    int n = j >> 7, k = j & 127;
    wt[98304 + n * 128 + k] = f2bf(cls_w1[k * 64 + n]);
  } else if (i < 107520) {
    int j = i - 106496;
    int n = j >> 6, k = j & 63;
    wt[106496 + n * 64 + k] = f2bf(cls_w2[k * 16 + n]);
  }
}

// ---------------- MFMA GEMM: C[M,128] = A[M,K] @ B[K,128] ----------------
#define LDS_STRIDE 72  // 64 + 8 pad: 144 B row stride -> 2-way bank alias (free, m136)
template<bool RELU_BIAS, bool OUTBF>
__global__ __launch_bounds__(256) void mfma_gemm_n128(const float* __restrict__ A,
                                                      const ushort* __restrict__ Bt,
                                                      const float* __restrict__ bias,
                                                      void* __restrict__ Cv, int M, int K) {
  __shared__ ushort sA[128 * LDS_STRIDE];
  __shared__ ushort sB[128 * LDS_STRIDE];
  const int tid = threadIdx.x;
  const int wave = tid >> 6, lane = tid & 63;
  const int q = lane >> 4, lm = lane & 15;
  const int wr = wave >> 1, wc = wave & 1;
  const int m0 = blockIdx.x * 128;

  f32x4 acc[4][4];
  #pragma unroll
  for (int i = 0; i < 4; i++)
    #pragma unroll
    for (int j = 0; j < 4; j++) acc[i][j] = {0.f, 0.f, 0.f, 0.f};

  for (int k0 = 0; k0 < K; k0 += 64) {
    __syncthreads();
    #pragma unroll
    for (int p = 0; p < 8; ++p) {
      int idx = p * 256 + tid;
      int r = idx >> 4;
      int c = (idx & 15) << 2;
      float4 v = make_float4(0.f, 0.f, 0.f, 0.f);
      if (m0 + r < M) v = *(const float4*)(A + (size_t)(m0 + r) * K + k0 + c);
      ushort4 u;
      u.x = f2bf(v.x); u.y = f2bf(v.y); u.z = f2bf(v.z); u.w = f2bf(v.w);
      *(ushort4*)&sA[r * LDS_STRIDE + c] = u;
    }
    #pragma unroll
    for (int p = 0; p < 4; ++p) {
      int idx = p * 256 + tid;
      int r = idx >> 3;
      int c = (idx & 7) << 3;
      bf16x8 v = *(const bf16x8*)(Bt + (size_t)r * K + k0 + c);
      *(bf16x8*)&sB[r * LDS_STRIDE + c] = v;
    }
    __syncthreads();
    #pragma unroll
    for (int ks = 0; ks < 2; ++ks) {
      bf16x8 af[4], bfv[4];
      #pragma unroll
      for (int t = 0; t < 4; ++t) {
        af[t]  = *(const bf16x8*)&sA[(wr * 64 + t * 16 + lm) * LDS_STRIDE + ks * 32 + q * 8];
        bfv[t] = *(const bf16x8*)&sB[(wc * 64 + t * 16 + lm) * LDS_STRIDE + ks * 32 + q * 8];
      }
      #pragma unroll
      for (int i = 0; i < 4; ++i)
        #pragma unroll
        for (int j = 0; j < 4; ++j)
          acc[i][j] = __builtin_amdgcn_mfma_f32_16x16x32_bf16(af[i], bfv[j], acc[i][j], 0, 0, 0);
    }
  }
  #pragma unroll
  for (int i = 0; i < 4; ++i) {
    #pragma unroll
    for (int r = 0; r < 4; ++r) {
      int row = m0 + wr * 64 + i * 16 + q * 4 + r;
      if (row < M) {
        #pragma unroll
        for (int j = 0; j < 4; ++j) {
          int colc = wc * 64 + j * 16 + lm;
          float v = acc[i][j][r];
          if (RELU_BIAS) { v += bias[colc]; v = fmaxf(v, 0.f); }
          if (OUTBF) ((ushort*)Cv)[(size_t)row * 128 + colc] = f2bf(v);
          else       ((float*)Cv)[(size_t)row * 128 + colc] = v;
        }
      }
    }
  }
}

// ---------------- attention logits (bf16 xh) ----------------
__global__ void att_logits_kernel(const ushort* __restrict__ xh,
                                  const float* __restrict__ att_s,
                                  const float* __restrict__ att_d,
                                  float* __restrict__ al_s, float* __restrict__ al_d, int n) {
  int t = blockIdx.x * blockDim.x + threadIdx.x;  // one per (node, head)
  if (t >= n * NHEAD) return;
  int head = t & 7;
  const unsigned* xw = (const unsigned*)(xh + (size_t)t * 16);
  const float* as = att_s + head * 16;
  const float* ad = att_d + head * 16;
  float ss = 0.f, dd = 0.f;
  #pragma unroll
  for (int i = 0; i < 8; ++i) {
    unsigned w = xw[i];
    float x0 = bflo(w), x1 = bfhi(w);
    ss = fmaf(x0, as[i * 2], fmaf(x1, as[i * 2 + 1], ss));
    dd = fmaf(x0, ad[i * 2], fmaf(x1, ad[i * 2 + 1], dd));
  }
  al_s[t] = ss;
  al_d[t] = dd;
}

// ---------------- pass 1: per-(node,head) max of e over incoming edges + self ----------
// leaky_relu is monotonic: max(e) = leaky(max(al_s[src]) + al_d)
__global__ void gat_max_kernel(const float* __restrict__ al_s,
                               const float* __restrict__ al_d,
                               const int* __restrict__ rowptr,
                               const int* __restrict__ col,
                               float* __restrict__ mmax, int n) {
  int t = blockIdx.x * blockDim.x + threadIdx.x;
  if (t >= n * NHEAD) return;
  int node = t >> 3, head = t & 7;
  int s0 = rowptr[node], s1 = rowptr[node + 1];
  float m = al_s[t];  // self-loop term al_s[node*8+head]
  for (int i = s0; i < s1; ++i) m = fmaxf(m, al_s[col[i] * NHEAD + head]);
  float e = m + al_d[t];
  mmax[t] = (e > 0.f) ? e : 0.2f * e;
}

// ---------------- pass 2: softmax-weighted aggregate (no rescale chain) --------------
// fused: + gat bias + residual + LayerNorm + ReLU
__global__ __launch_bounds__(256) void gat_aggregate(
    const ushort* __restrict__ xh, const float* __restrict__ al_s,
    const float* __restrict__ al_d, const float* __restrict__ mmax,
    const int* __restrict__ rowptr, const int* __restrict__ col,
    const float* __restrict__ h_res, const float* __restrict__ gb,
    const float* __restrict__ lng, const float* __restrict__ lnb,
    float* __restrict__ h_out, int n) {
  int lane = threadIdx.x & 63;
  int node = (blockIdx.x * blockDim.x + threadIdx.x) >> 6;
  if (node >= n) return;
  int head = lane >> 3;
  const unsigned* xw = (const unsigned*)xh;  // 2 bf16 channels per dword per lane
  float ald = al_d[node * NHEAD + head];
  float m = mmax[node * NHEAD + head];
  int start = rowptr[node], end = rowptr[node + 1];
  int sP = (start < end) ? col[start] : node;
  float eP = al_s[sP * NHEAD + head];
  unsigned xP = xw[(size_t)sP * 64 + lane];
  float denom = 0.f, acc0 = 0.f, acc1 = 0.f;
  for (int i = start; i <= end; ++i) {   // last iteration = self loop
    float e = eP + ald;
    unsigned xc = xP;
    int i2 = i + 1;
    if (i2 <= end) {
      int s2 = (i2 < end) ? col[i2] : node;
      eP = al_s[s2 * NHEAD + head];
      xP = xw[(size_t)s2 * 64 + lane];
    }
    e = (e > 0.f) ? e : 0.2f * e;
    float p = __expf(e - m);           // m >= e always; one term hits p=1
    denom += p;
    acc0 = fmaf(p, bflo(xc), acc0);
    acc1 = fmaf(p, bfhi(xc), acc1);
  }
  float inv = 1.f / denom;             // denom >= 1 by construction
  int c0 = lane * 2, c1 = c0 + 1;
  float2 hr = ((const float2*)h_res)[(size_t)node * 64 + lane];
  float v0 = acc0 * inv + gb[c0] + hr.x;
  float v1 = acc1 * inv + gb[c1] + hr.y;
  float sum = v0 + v1;
  #pragma unroll
  for (int off = 32; off; off >>= 1) sum += __shfl_xor(sum, off);
  float mean = sum * (1.f / 128.f);
  float d0 = v0 - mean, d1 = v1 - mean;
  float sq = d0 * d0 + d1 * d1;
  #pragma unroll
  for (int off = 32; off; off >>= 1) sq += __shfl_xor(sq, off);
  float rstd = rsqrtf(sq * (1.f / 128.f) + 1e-5f);
  float o0 = fmaxf(d0 * rstd * lng[c0] + lnb[c0], 0.f);
  float o1 = fmaxf(d1 * rstd * lng[c1] + lnb[c1], 0.f);
  ((float2*)h_out)[(size_t)node * 64 + lane] = make_float2(o0, o1);
}

// ---------------- MFMA classifier ----------------
#define CSTR 136
#define HSTR 72
__global__ __launch_bounds__(256) void classifier_mfma(
    const float* __restrict__ h, const ushort* __restrict__ w1t,
    const float* __restrict__ b1, const ushort* __restrict__ w2t,
    const float* __restrict__ b2, float* __restrict__ out, int n) {
  __shared__ ushort sA[128 * CSTR];
  __shared__ ushort sB[64 * CSTR];
  __shared__ ushort sHid[128 * HSTR];
  const int tid = threadIdx.x;
  const int wave = tid >> 6, lane = tid & 63;
  const int q = lane >> 4, lm = lane & 15;
  const int wr = wave >> 1, wc = wave & 1;
  const int m0 = blockIdx.x * 128;

  #pragma unroll
  for (int p = 0; p < 16; ++p) {
    int idx = p * 256 + tid;
    int r = idx >> 5;
    int c = (idx & 31) << 2;
    float4 v = make_float4(0.f, 0.f, 0.f, 0.f);
    if (m0 + r < n) v = *(const float4*)(h + (size_t)(m0 + r) * 128 + c);
    ushort4 u;
    u.x = f2bf(v.x); u.y = f2bf(v.y); u.z = f2bf(v.z); u.w = f2bf(v.w);
    *(ushort4*)&sA[r * CSTR + c] = u;
  }
  #pragma unroll
  for (int p = 0; p < 4; ++p) {
    int idx = p * 256 + tid;
    int r = idx >> 4;
    int c = (idx & 15) << 3;
    *(bf16x8*)&sB[r * CSTR + c] = *(const bf16x8*)(w1t + r * 128 + c);
  }
  __syncthreads();

  f32x4 acc[4][2];
  #pragma unroll
  for (int i = 0; i < 4; ++i)
    #pragma unroll
    for (int j = 0; j < 2; ++j) acc[i][j] = {0.f, 0.f, 0.f, 0.f};
  #pragma unroll
  for (int ks = 0; ks < 4; ++ks) {
    bf16x8 af[4], bfv[2];
    #pragma unroll
    for (int t = 0; t < 4; ++t)
      af[t] = *(const bf16x8*)&sA[(wr * 64 + t * 16 + lm) * CSTR + ks * 32 + q * 8];
    #pragma unroll
    for (int j = 0; j < 2; ++j)
      bfv[j] = *(const bf16x8*)&sB[(wc * 32 + j * 16 + lm) * CSTR + ks * 32 + q * 8];
    #pragma unroll
    for (int i = 0; i < 4; ++i)
      #pragma unroll
      for (int j = 0; j < 2; ++j)
        acc[i][j] = __builtin_amdgcn_mfma_f32_16x16x32_bf16(af[i], bfv[j], acc[i][j], 0, 0, 0);
  }
  #pragma unroll
  for (int i = 0; i < 4; ++i) {
    #pragma unroll
    for (int j = 0; j < 2; ++j) {
      int colc = wc * 32 + j * 16 + lm;
      float bb = b1[colc];
      #pragma unroll
      for (int r = 0; r < 4; ++r) {
        int row = wr * 64 + i * 16 + q * 4 + r;
        float v = fmaxf(acc[i][j][r] + bb, 0.f);
        sHid[row * HSTR + colc] = f2bf(v);
      }
    }
  }
  __syncthreads();

  f32x4 acc2[2] = {{0.f, 0.f, 0.f, 0.f}, {0.f, 0.f, 0.f, 0.f}};
  #pragma unroll
  for (int ks = 0; ks < 2; ++ks) {
    bf16x8 b2f = *(const bf16x8*)(w2t + lm * 64 + ks * 32 + q * 8);
    #pragma unroll
    for (int t = 0; t < 2; ++t) {
      bf16x8 a2 = *(const bf16x8*)&sHid[(wave * 32 + t * 16 + lm) * HSTR + ks * 32 + q * 8];
      acc2[t] = __builtin_amdgcn_mfma_f32_16x16x32_bf16(a2, b2f, acc2[t], 0, 0, 0);
    }
  }
  float bb2 = b2[lm];
  #pragma unroll
  for (int t = 0; t < 2; ++t) {
    #pragma unroll
    for (int r = 0; r < 4; ++r) {
      int row = m0 + wave * 32 + t * 16 + q * 4 + r;
      float lg = acc2[t][r] + bb2;
      float mx = lg;
      #pragma unroll
      for (int off = 8; off; off >>= 1) mx = fmaxf(mx, __shfl_xor(mx, off, 16));
      float se = __expf(lg - mx);
      #pragma unroll
      for (int off = 8; off; off >>= 1) se += __shfl_xor(se, off, 16);
      if (row < n) out[(size_t)row * 16 + lm] = lg - mx - __logf(se);
    }
  }
}

// ---------------- launch ----------------
extern "C" void kernel_launch(void* const* d_in, const int* in_sizes, int n_in,
                              void* d_out, int out_size, void* d_ws, size_t ws_size,
                              hipStream_t stream) {
  const float* x       = (const float*)d_in[0];
  const int*   ei      = (const int*)d_in[1];
  const float* proj_w  = (const float*)d_in[2];
  const float* proj_b  = (const float*)d_in[3];
  const float* lin_w   = (const float*)d_in[4];
  const float* att_src = (const float*)d_in[5];
  const float* att_dst = (const float*)d_in[6];
  const float* gat_b   = (const float*)d_in[7];
  const float* ln_g    = (const float*)d_in[8];
  const float* ln_b    = (const float*)d_in[9];
  const float* cls_w1  = (const float*)d_in[10];
  const float* cls_b1  = (const float*)d_in[11];
  const float* cls_w2  = (const float*)d_in[12];
  const float* cls_b2  = (const float*)d_in[13];
  float* outp = (float*)d_out;

  const int N = NN, E = EE;
  ushort* wt   = (ushort*)d_ws;                 // 107520 ushorts, pad to 108544
  float* h0    = (float*)d_ws + 54272;
  float* h1    = h0 + (size_t)N * 128;
  ushort* xh_u = (ushort*)(h1 + (size_t)N * 128);   // N*128 bf16 = N*64 floats
  float* als   = (float*)(xh_u + (size_t)N * 128);
  float* ald   = als + (size_t)N * NHEAD;
  float* mmax  = ald + (size_t)N * NHEAD;
  int* counts  = (int*)(mmax + (size_t)N * NHEAD);
  int* rowptr  = counts + N;
  int* woff    = rowptr + N + 1;
  int* col     = woff + N;
  int* bsum    = col + E;
  int* boff    = bsum + SCAN_NBLK;

  const int* e_src = ei;
  const int* e_dst = ei + E;

  prep_weights<<<(107520 + 255) / 256, 256, 0, stream>>>(proj_w, lin_w, cls_w1, cls_w2, wt);

  zero_ints<<<(N + 255) / 256, 256, 0, stream>>>(counts, N);
  hist_kernel<<<(E + 255) / 256, 256, 0, stream>>>(e_dst, counts, E);
  partial_sums<<<SCAN_NBLK, 256, 0, stream>>>(counts, bsum, N);
  scan_bsums<<<1, 256, 0, stream>>>(bsum, boff, SCAN_NBLK);
  final_scan<<<SCAN_NBLK, 256, 0, stream>>>(counts, boff, rowptr, woff, N);
  scatter_kernel<<<(E + 255) / 256, 256, 0, stream>>>(e_src, e_dst, woff, col, E);

  const int gblocks = (N + 127) / 128;
  mfma_gemm_n128<true, false><<<gblocks, 256, 0, stream>>>(x, wt, proj_b, h0, N, DIN);

  float* hc = h0;
  float* hn = h1;
  for (int l = 0; l < 3; ++l) {
    mfma_gemm_n128<false, true><<<gblocks, 256, 0, stream>>>(
        hc, wt + 49152 + l * 16384, nullptr, xh_u, N, 128);
    att_logits_kernel<<<(N * NHEAD + 255) / 256, 256, 0, stream>>>(
        xh_u, att_src + l * 128, att_dst + l * 128, als, ald, N);
    gat_max_kernel<<<(N * NHEAD + 255) / 256, 256, 0, stream>>>(
        als, ald, rowptr, col, mmax, N);
    gat_aggregate<<<(N + 3) / 4, 256, 0, stream>>>(
        xh_u, als, ald, mmax, rowptr, col, hc, gat_b + l * 128, ln_g + l * 128,
        ln_b + l * 128, hn, N);
    float* t = hc; hc = hn; hn = t;
  }
  classifier_mfma<<<gblocks, 256, 0, stream>>>(hc, wt + 98304, cls_b1, wt + 106496, cls_b2, outp, N);
}

// Round 7
// 405.799 us; speedup vs baseline: 1.2991x; 1.2991x over previous
//
#include <hip/hip_runtime.h>
#include <hip/hip_bf16.h>
#include <math.h>

#define NN 50000
#define EE 500000
#define DIN 384
#define HIDD 128
#define NHEAD 8
#define OUTD 16

typedef __attribute__((ext_vector_type(8))) __bf16 bf16x8;
typedef __attribute__((ext_vector_type(4))) float f32x4;

__device__ __forceinline__ ushort f2bf(float f) {
  union { float f; unsigned u; } v; v.f = f;
  unsigned r = v.u + 0x7fffu + ((v.u >> 16) & 1u);
  return (ushort)(r >> 16);
}
__device__ __forceinline__ float bflo(unsigned w) {
  union { unsigned u; float f; } v; v.u = w << 16; return v.f;
}
__device__ __forceinline__ float bfhi(unsigned w) {
  union { unsigned u; float f; } v; v.u = w & 0xffff0000u; return v.f;
}

// ---------------- CSR build ----------------
__global__ void zero_ints(int* p, int n) {
  int i = blockIdx.x * blockDim.x + threadIdx.x;
  if (i < n) p[i] = 0;
}

__global__ void hist_kernel(const int* __restrict__ dst, int* __restrict__ counts, int e) {
  int i = blockIdx.x * blockDim.x + threadIdx.x;
  if (i < e) atomicAdd(&counts[dst[i]], 1);
}

#define SCAN_BS 256
#define SCAN_NBLK ((NN + SCAN_BS - 1) / SCAN_BS)  // 196

__global__ __launch_bounds__(256) void partial_sums(const int* __restrict__ counts,
                                                    int* __restrict__ bsum, int n) {
  __shared__ int red[256];
  int i = blockIdx.x * 256 + threadIdx.x;
  red[threadIdx.x] = (i < n) ? counts[i] : 0;
  __syncthreads();
  #pragma unroll
  for (int off = 128; off; off >>= 1) {
    if (threadIdx.x < off) red[threadIdx.x] += red[threadIdx.x + off];
    __syncthreads();
  }
  if (threadIdx.x == 0) bsum[blockIdx.x] = red[0];
}

__global__ __launch_bounds__(256) void scan_bsums(const int* __restrict__ bsum,
                                                  int* __restrict__ boff, int nb) {
  __shared__ int buf[256];
  int t = threadIdx.x;
  int v = (t < nb) ? bsum[t] : 0;
  buf[t] = v;
  __syncthreads();
  #pragma unroll
  for (int off = 1; off < 256; off <<= 1) {
    int u = (t >= off) ? buf[t - off] : 0;
    __syncthreads();
    buf[t] += u;
    __syncthreads();
  }
  if (t < nb) boff[t] = buf[t] - v;
}

__global__ __launch_bounds__(256) void final_scan(const int* __restrict__ counts,
                                                  const int* __restrict__ boff,
                                                  int* __restrict__ rowptr,
                                                  int* __restrict__ woff, int n) {
  __shared__ int buf[256];
  int i = blockIdx.x * 256 + threadIdx.x;
  int t = threadIdx.x;
  int v = (i < n) ? counts[i] : 0;
  buf[t] = v;
  __syncthreads();
  #pragma unroll
  for (int off = 1; off < 256; off <<= 1) {
    int u = (t >= off) ? buf[t - off] : 0;
    __syncthreads();
    buf[t] += u;
    __syncthreads();
  }
  int excl = boff[blockIdx.x] + buf[t] - v;
  if (i < n) { rowptr[i] = excl; woff[i] = excl; }
  if (i == n - 1) rowptr[n] = excl + v;
}

__global__ void scatter_kernel(const int* __restrict__ src, const int* __restrict__ dst,
                               int* __restrict__ woff, int* __restrict__ col, int e) {
  int i = blockIdx.x * blockDim.x + threadIdx.x;
  if (i < e) {
    int p = atomicAdd(&woff[dst[i]], 1);
    col[p] = src[i];
  }
}

// ---------------- weight prep ----------------
// wt layout (ushort):
//  [0..49151]          proj_wt [n=128][k=384]
//  [49152 + l*16384]   lin_wt_l [n=128][k=128]   (l=0..2)
//  [98304..106495]     cls_w1t [n=64][k=128]
//  [106496..107519]    cls_w2t [n=16][k=64]
__global__ void prep_weights(const float* __restrict__ proj_w,
                             const float* __restrict__ lin_w,
                             const float* __restrict__ cls_w1,
                             const float* __restrict__ cls_w2,
                             ushort* __restrict__ wt) {
  int i = blockIdx.x * blockDim.x + threadIdx.x;
  if (i < 49152) {
    int k = i >> 7, n = i & 127;
    wt[n * 384 + k] = f2bf(proj_w[i]);
  } else if (i < 98304) {
    int j = i - 49152;
    int l = j >> 14, rem = j & 16383;
    int k = rem >> 7, n = rem & 127;
    wt[49152 + l * 16384 + n * 128 + k] = f2bf(lin_w[j]);
  } else if (i < 106496) {
    int j = i - 98304;
    int n = j >> 7, k = j & 127;
    wt[98304 + n * 128 + k] = f2bf(cls_w1[k * 64 + n]);
  } else if (i < 107520) {
    int j = i - 106496;
    int n = j >> 6, k = j & 63;
    wt[106496 + n * 64 + k] = f2bf(cls_w2[k * 16 + n]);
  }
}

// ---------------- MFMA GEMM: C[M,128] = A[M,K] @ B[K,128] ----------------
#define LDS_STRIDE 72  // 64 + 8 pad: 2-way bank alias only (free, m136)
template<bool RELU_BIAS, bool OUTBF>
__global__ __launch_bounds__(256) void mfma_gemm_n128(const float* __restrict__ A,
                                                      const ushort* __restrict__ Bt,
                                                      const float* __restrict__ bias,
                                                      void* __restrict__ Cv, int M, int K) {
  __shared__ ushort sA[128 * LDS_STRIDE];
  __shared__ ushort sB[128 * LDS_STRIDE];
  const int tid = threadIdx.x;
  const int wave = tid >> 6, lane = tid & 63;
  const int q = lane >> 4, lm = lane & 15;
  const int wr = wave >> 1, wc = wave & 1;
  const int m0 = blockIdx.x * 128;

  f32x4 acc[4][4];
  #pragma unroll
  for (int i = 0; i < 4; i++)
    #pragma unroll
    for (int j = 0; j < 4; j++) acc[i][j] = {0.f, 0.f, 0.f, 0.f};

  for (int k0 = 0; k0 < K; k0 += 64) {
    __syncthreads();
    #pragma unroll
    for (int p = 0; p < 8; ++p) {
      int idx = p * 256 + tid;
      int r = idx >> 4;
      int c = (idx & 15) << 2;
      float4 v = make_float4(0.f, 0.f, 0.f, 0.f);
      if (m0 + r < M) v = *(const float4*)(A + (size_t)(m0 + r) * K + k0 + c);
      ushort4 u;
      u.x = f2bf(v.x); u.y = f2bf(v.y); u.z = f2bf(v.z); u.w = f2bf(v.w);
      *(ushort4*)&sA[r * LDS_STRIDE + c] = u;
    }
    #pragma unroll
    for (int p = 0; p < 4; ++p) {
      int idx = p * 256 + tid;
      int r = idx >> 3;
      int c = (idx & 7) << 3;
      bf16x8 v = *(const bf16x8*)(Bt + (size_t)r * K + k0 + c);
      *(bf16x8*)&sB[r * LDS_STRIDE + c] = v;
    }
    __syncthreads();
    #pragma unroll
    for (int ks = 0; ks < 2; ++ks) {
      bf16x8 af[4], bfv[4];
      #pragma unroll
      for (int t = 0; t < 4; ++t) {
        af[t]  = *(const bf16x8*)&sA[(wr * 64 + t * 16 + lm) * LDS_STRIDE + ks * 32 + q * 8];
        bfv[t] = *(const bf16x8*)&sB[(wc * 64 + t * 16 + lm) * LDS_STRIDE + ks * 32 + q * 8];
      }
      #pragma unroll
      for (int i = 0; i < 4; ++i)
        #pragma unroll
        for (int j = 0; j < 4; ++j)
          acc[i][j] = __builtin_amdgcn_mfma_f32_16x16x32_bf16(af[i], bfv[j], acc[i][j], 0, 0, 0);
    }
  }
  #pragma unroll
  for (int i = 0; i < 4; ++i) {
    #pragma unroll
    for (int r = 0; r < 4; ++r) {
      int row = m0 + wr * 64 + i * 16 + q * 4 + r;
      if (row < M) {
        #pragma unroll
        for (int j = 0; j < 4; ++j) {
          int colc = wc * 64 + j * 16 + lm;
          float v = acc[i][j][r];
          if (RELU_BIAS) { v += bias[colc]; v = fmaxf(v, 0.f); }
          if (OUTBF) ((ushort*)Cv)[(size_t)row * 128 + colc] = f2bf(v);
          else       ((float*)Cv)[(size_t)row * 128 + colc] = v;
        }
      }
    }
  }
}

// ---------------- attention logits (bf16 xh) ----------------
__global__ void att_logits_kernel(const ushort* __restrict__ xh,
                                  const float* __restrict__ att_s,
                                  const float* __restrict__ att_d,
                                  float* __restrict__ al_s, float* __restrict__ al_d, int n) {
  int t = blockIdx.x * blockDim.x + threadIdx.x;  // one per (node, head)
  if (t >= n * NHEAD) return;
  int head = t & 7;
  const unsigned* xw = (const unsigned*)(xh + (size_t)t * 16);
  const float* as = att_s + head * 16;
  const float* ad = att_d + head * 16;
  float ss = 0.f, dd = 0.f;
  #pragma unroll
  for (int i = 0; i < 8; ++i) {
    unsigned w = xw[i];
    float x0 = bflo(w), x1 = bfhi(w);
    ss = fmaf(x0, as[i * 2], fmaf(x1, as[i * 2 + 1], ss));
    dd = fmaf(x0, ad[i * 2], fmaf(x1, ad[i * 2 + 1], dd));
  }
  al_s[t] = ss;
  al_d[t] = dd;
}

// ---------------- GAT aggregation: 8-edge-parallel chunk-online softmax ----------------
// one wave per node; per chunk of 8 edges all gathers issue independently (8-deep MLP)
__global__ __launch_bounds__(256) void gat_aggregate(
    const ushort* __restrict__ xh, const float* __restrict__ al_s,
    const float* __restrict__ al_d, const int* __restrict__ rowptr,
    const int* __restrict__ col, const float* __restrict__ h_res,
    const float* __restrict__ gb, const float* __restrict__ lng,
    const float* __restrict__ lnb, float* __restrict__ h_out, int n) {
  const int lane = threadIdx.x & 63;
  const int node = (blockIdx.x * blockDim.x + threadIdx.x) >> 6;
  if (node >= n) return;
  const int e8 = lane >> 3;     // compute mapping: edge-in-chunk
  const int hh = lane & 7;      // compute mapping: head
  const int head = lane >> 3;   // accumulate mapping: head (channels 2*lane, 2*lane+1)
  const unsigned* xw_base = (const unsigned*)xh;

  const int start = rowptr[node], end = rowptr[node + 1];
  const int T = end - start + 1;              // + self-loop (item T-1)
  const float ald_c = al_d[node * 8 + hh];    // for compute mapping

  float m = -INFINITY, denom = 0.f, acc0 = 0.f, acc1 = 0.f;

  for (int c = 0; c < T; c += 8) {
    int it = c + e8;
    bool valid = it < T;
    int idx = start + it;
    int s = (valid && idx < end) ? col[idx] : node;  // self-loop and pad -> node (safe addr)
    float e = al_s[s * 8 + hh] + ald_c;
    e = (e > 0.f) ? e : 0.2f * e;               // leaky_relu
    if (!valid) e = -INFINITY;
    // chunk max over edge dim (stride-8 lanes), per hh
    float cm = e;
    cm = fmaxf(cm, __shfl_xor(cm, 8));
    cm = fmaxf(cm, __shfl_xor(cm, 16));
    cm = fmaxf(cm, __shfl_xor(cm, 32));
    // running max in ACC mapping (my head), and its value in COMPUTE mapping (my hh)
    float newm = fmaxf(m, __shfl(cm, head));    // lane 'head' holds cm for hh==head
    float newm_c = __shfl(newm, hh * 8);        // lane hh*8 holds newm for head==hh
    float p_lane = __expf(e - newm_c);          // 0 for invalid lanes
    float scale = __expf(m - newm);             // 0 on first chunk (m=-inf)
    m = newm;
    // gather 8 xh rows — fully independent 256B loads, all in flight
    unsigned xg[8];
    int sj[8];
    #pragma unroll
    for (int j = 0; j < 8; ++j) sj[j] = __shfl(s, j * 8);
    #pragma unroll
    for (int j = 0; j < 8; ++j) xg[j] = xw_base[(size_t)sj[j] * 64 + lane];
    denom *= scale; acc0 *= scale; acc1 *= scale;
    #pragma unroll
    for (int j = 0; j < 8; ++j) {
      float pj = __shfl(p_lane, j * 8 + head);  // p for (edge j, my acc head)
      denom += pj;
      acc0 = fmaf(pj, bflo(xg[j]), acc0);
      acc1 = fmaf(pj, bfhi(xg[j]), acc1);
    }
  }

  float inv = 1.f / denom;                      // denom >= ~1 (max item has p=1)
  int c0 = lane * 2, c1 = c0 + 1;
  float2 hr = ((const float2*)h_res)[(size_t)node * 64 + lane];
  float v0 = acc0 * inv + gb[c0] + hr.x;
  float v1 = acc1 * inv + gb[c1] + hr.y;
  float sum = v0 + v1;
  #pragma unroll
  for (int off = 32; off; off >>= 1) sum += __shfl_xor(sum, off);
  float mean = sum * (1.f / 128.f);
  float d0 = v0 - mean, d1 = v1 - mean;
  float sq = d0 * d0 + d1 * d1;
  #pragma unroll
  for (int off = 32; off; off >>= 1) sq += __shfl_xor(sq, off);
  float rstd = rsqrtf(sq * (1.f / 128.f) + 1e-5f);
  float o0 = fmaxf(d0 * rstd * lng[c0] + lnb[c0], 0.f);
  float o1 = fmaxf(d1 * rstd * lng[c1] + lnb[c1], 0.f);
  ((float2*)h_out)[(size_t)node * 64 + lane] = make_float2(o0, o1);
}

// ---------------- MFMA classifier ----------------
#define CSTR 136
#define HSTR 72
__global__ __launch_bounds__(256) void classifier_mfma(
    const float* __restrict__ h, const ushort* __restrict__ w1t,
    const float* __restrict__ b1, const ushort* __restrict__ w2t,
    const float* __restrict__ b2, float* __restrict__ out, int n) {
  __shared__ ushort sA[128 * CSTR];
  __shared__ ushort sB[64 * CSTR];
  __shared__ ushort sHid[128 * HSTR];
  const int tid = threadIdx.x;
  const int wave = tid >> 6, lane = tid & 63;
  const int q = lane >> 4, lm = lane & 15;
  const int wr = wave >> 1, wc = wave & 1;
  const int m0 = blockIdx.x * 128;

  #pragma unroll
  for (int p = 0; p < 16; ++p) {
    int idx = p * 256 + tid;
    int r = idx >> 5;
    int c = (idx & 31) << 2;
    float4 v = make_float4(0.f, 0.f, 0.f, 0.f);
    if (m0 + r < n) v = *(const float4*)(h + (size_t)(m0 + r) * 128 + c);
    ushort4 u;
    u.x = f2bf(v.x); u.y = f2bf(v.y); u.z = f2bf(v.z); u.w = f2bf(v.w);
    *(ushort4*)&sA[r * CSTR + c] = u;
  }
  #pragma unroll
  for (int p = 0; p < 4; ++p) {
    int idx = p * 256 + tid;
    int r = idx >> 4;
    int c = (idx & 15) << 3;
    *(bf16x8*)&sB[r * CSTR + c] = *(const bf16x8*)(w1t + r * 128 + c);
  }
  __syncthreads();

  f32x4 acc[4][2];
  #pragma unroll
  for (int i = 0; i < 4; ++i)
    #pragma unroll
    for (int j = 0; j < 2; ++j) acc[i][j] = {0.f, 0.f, 0.f, 0.f};
  #pragma unroll
  for (int ks = 0; ks < 4; ++ks) {
    bf16x8 af[4], bfv[2];
    #pragma unroll
    for (int t = 0; t < 4; ++t)
      af[t] = *(const bf16x8*)&sA[(wr * 64 + t * 16 + lm) * CSTR + ks * 32 + q * 8];
    #pragma unroll
    for (int j = 0; j < 2; ++j)
      bfv[j] = *(const bf16x8*)&sB[(wc * 32 + j * 16 + lm) * CSTR + ks * 32 + q * 8];
    #pragma unroll
    for (int i = 0; i < 4; ++i)
      #pragma unroll
      for (int j = 0; j < 2; ++j)
        acc[i][j] = __builtin_amdgcn_mfma_f32_16x16x32_bf16(af[i], bfv[j], acc[i][j], 0, 0, 0);
  }
  #pragma unroll
  for (int i = 0; i < 4; ++i) {
    #pragma unroll
    for (int j = 0; j < 2; ++j) {
      int colc = wc * 32 + j * 16 + lm;
      float bb = b1[colc];
      #pragma unroll
      for (int r = 0; r < 4; ++r) {
        int row = wr * 64 + i * 16 + q * 4 + r;
        float v = fmaxf(acc[i][j][r] + bb, 0.f);
        sHid[row * HSTR + colc] = f2bf(v);
      }
    }
  }
  __syncthreads();

  f32x4 acc2[2] = {{0.f, 0.f, 0.f, 0.f}, {0.f, 0.f, 0.f, 0.f}};
  #pragma unroll
  for (int ks = 0; ks < 2; ++ks) {
    bf16x8 b2f = *(const bf16x8*)(w2t + lm * 64 + ks * 32 + q * 8);
    #pragma unroll
    for (int t = 0; t < 2; ++t) {
      bf16x8 a2 = *(const bf16x8*)&sHid[(wave * 32 + t * 16 + lm) * HSTR + ks * 32 + q * 8];
      acc2[t] = __builtin_amdgcn_mfma_f32_16x16x32_bf16(a2, b2f, acc2[t], 0, 0, 0);
    }
  }
  float bb2 = b2[lm];
  #pragma unroll
  for (int t = 0; t < 2; ++t) {
    #pragma unroll
    for (int r = 0; r < 4; ++r) {
      int row = m0 + wave * 32 + t * 16 + q * 4 + r;
      float lg = acc2[t][r] + bb2;
      float mx = lg;
      #pragma unroll
      for (int off = 8; off; off >>= 1) mx = fmaxf(mx, __shfl_xor(mx, off, 16));
      float se = __expf(lg - mx);
      #pragma unroll
      for (int off = 8; off; off >>= 1) se += __shfl_xor(se, off, 16);
      if (row < n) out[(size_t)row * 16 + lm] = lg - mx - __logf(se);
    }
  }
}

// ---------------- launch ----------------
extern "C" void kernel_launch(void* const* d_in, const int* in_sizes, int n_in,
                              void* d_out, int out_size, void* d_ws, size_t ws_size,
                              hipStream_t stream) {
  const float* x       = (const float*)d_in[0];
  const int*   ei      = (const int*)d_in[1];
  const float* proj_w  = (const float*)d_in[2];
  const float* proj_b  = (const float*)d_in[3];
  const float* lin_w   = (const float*)d_in[4];
  const float* att_src = (const float*)d_in[5];
  const float* att_dst = (const float*)d_in[6];
  const float* gat_b   = (const float*)d_in[7];
  const float* ln_g    = (const float*)d_in[8];
  const float* ln_b    = (const float*)d_in[9];
  const float* cls_w1  = (const float*)d_in[10];
  const float* cls_b1  = (const float*)d_in[11];
  const float* cls_w2  = (const float*)d_in[12];
  const float* cls_b2  = (const float*)d_in[13];
  float* outp = (float*)d_out;

  const int N = NN, E = EE;
  ushort* wt   = (ushort*)d_ws;                 // 107520 ushorts, pad to 108544
  float* h0    = (float*)d_ws + 54272;
  float* h1    = h0 + (size_t)N * 128;
  ushort* xh_u = (ushort*)(h1 + (size_t)N * 128);   // N*128 bf16
  float* als   = (float*)(xh_u + (size_t)N * 128);
  float* ald   = als + (size_t)N * NHEAD;
  int* counts  = (int*)(ald + (size_t)N * NHEAD);
  int* rowptr  = counts + N;
  int* woff    = rowptr + N + 1;
  int* col     = woff + N;
  int* bsum    = col + E;
  int* boff    = bsum + SCAN_NBLK;

  const int* e_src = ei;
  const int* e_dst = ei + E;

  prep_weights<<<(107520 + 255) / 256, 256, 0, stream>>>(proj_w, lin_w, cls_w1, cls_w2, wt);

  zero_ints<<<(N + 255) / 256, 256, 0, stream>>>(counts, N);
  hist_kernel<<<(E + 255) / 256, 256, 0, stream>>>(e_dst, counts, E);
  partial_sums<<<SCAN_NBLK, 256, 0, stream>>>(counts, bsum, N);
  scan_bsums<<<1, 256, 0, stream>>>(bsum, boff, SCAN_NBLK);
  final_scan<<<SCAN_NBLK, 256, 0, stream>>>(counts, boff, rowptr, woff, N);
  scatter_kernel<<<(E + 255) / 256, 256, 0, stream>>>(e_src, e_dst, woff, col, E);

  const int gblocks = (N + 127) / 128;
  mfma_gemm_n128<true, false><<<gblocks, 256, 0, stream>>>(x, wt, proj_b, h0, N, DIN);

  float* hc = h0;
  float* hn = h1;
  for (int l = 0; l < 3; ++l) {
    mfma_gemm_n128<false, true><<<gblocks, 256, 0, stream>>>(
        hc, wt + 49152 + l * 16384, nullptr, xh_u, N, 128);
    att_logits_kernel<<<(N * NHEAD + 255) / 256, 256, 0, stream>>>(
        xh_u, att_src + l * 128, att_dst + l * 128, als, ald, N);
    gat_aggregate<<<(N + 3) / 4, 256, 0, stream>>>(
        xh_u, als, ald, rowptr, col, hc, gat_b + l * 128, ln_g + l * 128,
        ln_b + l * 128, hn, N);
    float* t = hc; hc = hn; hn = t;
  }
  classifier_mfma<<<gblocks, 256, 0, stream>>>(hc, wt + 98304, cls_b1, wt + 106496, cls_b2, outp, N);
}

// Round 8
// 381.380 us; speedup vs baseline: 1.3823x; 1.0640x over previous
//
#include <hip/hip_runtime.h>
#include <hip/hip_bf16.h>
#include <math.h>

#define NN 50000
#define EE 500000
#define DIN 384
#define HIDD 128
#define NHEAD 8
#define OUTD 16

typedef __attribute__((ext_vector_type(8))) __bf16 bf16x8;
typedef __attribute__((ext_vector_type(4))) float f32x4;

__device__ __forceinline__ ushort f2bf(float f) {
  union { float f; unsigned u; } v; v.f = f;
  unsigned r = v.u + 0x7fffu + ((v.u >> 16) & 1u);
  return (ushort)(r >> 16);
}
__device__ __forceinline__ float bflo(unsigned w) {
  union { unsigned u; float f; } v; v.u = w << 16; return v.f;
}
__device__ __forceinline__ float bfhi(unsigned w) {
  union { unsigned u; float f; } v; v.u = w & 0xffff0000u; return v.f;
}

// ---------------- CSR build ----------------
__global__ void zero_ints(int* p, int n) {
  int i = blockIdx.x * blockDim.x + threadIdx.x;
  if (i < n) p[i] = 0;
}

__global__ void hist_kernel(const int* __restrict__ dst, int* __restrict__ counts, int e) {
  int i = blockIdx.x * blockDim.x + threadIdx.x;
  if (i < e) atomicAdd(&counts[dst[i]], 1);
}

#define SCAN_BS 256
#define SCAN_NBLK ((NN + SCAN_BS - 1) / SCAN_BS)  // 196

__global__ __launch_bounds__(256) void partial_sums(const int* __restrict__ counts,
                                                    int* __restrict__ bsum, int n) {
  __shared__ int red[256];
  int i = blockIdx.x * 256 + threadIdx.x;
  red[threadIdx.x] = (i < n) ? counts[i] : 0;
  __syncthreads();
  #pragma unroll
  for (int off = 128; off; off >>= 1) {
    if (threadIdx.x < off) red[threadIdx.x] += red[threadIdx.x + off];
    __syncthreads();
  }
  if (threadIdx.x == 0) bsum[blockIdx.x] = red[0];
}

__global__ __launch_bounds__(256) void scan_bsums(const int* __restrict__ bsum,
                                                  int* __restrict__ boff, int nb) {
  __shared__ int buf[256];
  int t = threadIdx.x;
  int v = (t < nb) ? bsum[t] : 0;
  buf[t] = v;
  __syncthreads();
  #pragma unroll
  for (int off = 1; off < 256; off <<= 1) {
    int u = (t >= off) ? buf[t - off] : 0;
    __syncthreads();
    buf[t] += u;
    __syncthreads();
  }
  if (t < nb) boff[t] = buf[t] - v;
}

__global__ __launch_bounds__(256) void final_scan(const int* __restrict__ counts,
                                                  const int* __restrict__ boff,
                                                  int* __restrict__ rowptr,
                                                  int* __restrict__ woff, int n) {
  __shared__ int buf[256];
  int i = blockIdx.x * 256 + threadIdx.x;
  int t = threadIdx.x;
  int v = (i < n) ? counts[i] : 0;
  buf[t] = v;
  __syncthreads();
  #pragma unroll
  for (int off = 1; off < 256; off <<= 1) {
    int u = (t >= off) ? buf[t - off] : 0;
    __syncthreads();
    buf[t] += u;
    __syncthreads();
  }
  int excl = boff[blockIdx.x] + buf[t] - v;
  if (i < n) { rowptr[i] = excl; woff[i] = excl; }
  if (i == n - 1) rowptr[n] = excl + v;
}

__global__ void scatter_kernel(const int* __restrict__ src, const int* __restrict__ dst,
                               int* __restrict__ woff, int* __restrict__ col, int e) {
  int i = blockIdx.x * blockDim.x + threadIdx.x;
  if (i < e) {
    int p = atomicAdd(&woff[dst[i]], 1);
    col[p] = src[i];
  }
}

// ---------------- weight prep ----------------
// wt layout (ushort):
//  [0..49151]          proj_wt [n=128][k=384]
//  [49152 + l*16384]   lin_wt_l [n=128][k=128]   (l=0..2)
//  [98304..106495]     cls_w1t [n=64][k=128]
//  [106496..107519]    cls_w2t [n=16][k=64]
__global__ void prep_weights(const float* __restrict__ proj_w,
                             const float* __restrict__ lin_w,
                             const float* __restrict__ cls_w1,
                             const float* __restrict__ cls_w2,
                             ushort* __restrict__ wt) {
  int i = blockIdx.x * blockDim.x + threadIdx.x;
  if (i < 49152) {
    int k = i >> 7, n = i & 127;
    wt[n * 384 + k] = f2bf(proj_w[i]);
  } else if (i < 98304) {
    int j = i - 49152;
    int l = j >> 14, rem = j & 16383;
    int k = rem >> 7, n = rem & 127;
    wt[49152 + l * 16384 + n * 128 + k] = f2bf(lin_w[j]);
  } else if (i < 106496) {
    int j = i - 98304;
    int n = j >> 7, k = j & 127;
    wt[98304 + n * 128 + k] = f2bf(cls_w1[k * 64 + n]);
  } else if (i < 107520) {
    int j = i - 106496;
    int n = j >> 6, k = j & 63;
    wt[106496 + n * 64 + k] = f2bf(cls_w2[k * 16 + n]);
  }
}

// ---------------- MFMA GEMM: C[M,128] = A[M,K] @ B[K,128], bf16 out ----------------
// 64-row M-tile (782 blocks -> ~3 blocks/CU). 4 waves in 2x2 grid, wave tile 32x64.
#define LDS_STRIDE 72  // 64 + 8 pad: 2-way bank alias only (free, m136)
template<typename AT, bool RELU_BIAS>
__global__ __launch_bounds__(256) void mfma_gemm64(const AT* __restrict__ A,
                                                   const ushort* __restrict__ Bt,
                                                   const float* __restrict__ bias,
                                                   ushort* __restrict__ C, int M, int K) {
  __shared__ ushort sA[64 * LDS_STRIDE];
  __shared__ ushort sB[128 * LDS_STRIDE];
  const int tid = threadIdx.x;
  const int wave = tid >> 6, lane = tid & 63;
  const int q = lane >> 4, lm = lane & 15;
  const int wr = wave >> 1, wc = wave & 1;
  const int m0 = blockIdx.x * 64;

  f32x4 acc[2][4];
  #pragma unroll
  for (int i = 0; i < 2; i++)
    #pragma unroll
    for (int j = 0; j < 4; j++) acc[i][j] = {0.f, 0.f, 0.f, 0.f};

  for (int k0 = 0; k0 < K; k0 += 64) {
    __syncthreads();
    // stage A: 64 rows x 64 cols -> bf16 LDS (row-clamped; epilogue guards stores)
    if constexpr (sizeof(AT) == 4) {
      #pragma unroll
      for (int p = 0; p < 4; ++p) {
        int idx = p * 256 + tid;
        int r = idx >> 4;
        int c = (idx & 15) << 2;
        int row = min(m0 + r, M - 1);
        float4 v = *(const float4*)((const float*)A + (size_t)row * K + k0 + c);
        ushort4 u;
        u.x = f2bf(v.x); u.y = f2bf(v.y); u.z = f2bf(v.z); u.w = f2bf(v.w);
        *(ushort4*)&sA[r * LDS_STRIDE + c] = u;
      }
    } else {
      #pragma unroll
      for (int p = 0; p < 2; ++p) {
        int idx = p * 256 + tid;
        int r = idx >> 3;
        int c = (idx & 7) << 3;
        int row = min(m0 + r, M - 1);
        *(bf16x8*)&sA[r * LDS_STRIDE + c] =
            *(const bf16x8*)((const ushort*)A + (size_t)row * K + k0 + c);
      }
    }
    // stage B: 128 rows (= C cols) x 64 cols bf16
    #pragma unroll
    for (int p = 0; p < 4; ++p) {
      int idx = p * 256 + tid;
      int r = idx >> 3;
      int c = (idx & 7) << 3;
      *(bf16x8*)&sB[r * LDS_STRIDE + c] = *(const bf16x8*)(Bt + (size_t)r * K + k0 + c);
    }
    __syncthreads();
    #pragma unroll
    for (int ks = 0; ks < 2; ++ks) {
      bf16x8 af[2], bfv[4];
      #pragma unroll
      for (int t = 0; t < 2; ++t)
        af[t] = *(const bf16x8*)&sA[(wr * 32 + t * 16 + lm) * LDS_STRIDE + ks * 32 + q * 8];
      #pragma unroll
      for (int t = 0; t < 4; ++t)
        bfv[t] = *(const bf16x8*)&sB[(wc * 64 + t * 16 + lm) * LDS_STRIDE + ks * 32 + q * 8];
      #pragma unroll
      for (int i = 0; i < 2; ++i)
        #pragma unroll
        for (int j = 0; j < 4; ++j)
          acc[i][j] = __builtin_amdgcn_mfma_f32_16x16x32_bf16(af[i], bfv[j], acc[i][j], 0, 0, 0);
    }
  }
  // epilogue: C/D layout col=lane&15, row=(lane>>4)*4+reg  [m89-verified]
  #pragma unroll
  for (int i = 0; i < 2; ++i) {
    #pragma unroll
    for (int r = 0; r < 4; ++r) {
      int row = m0 + wr * 32 + i * 16 + q * 4 + r;
      if (row < M) {
        #pragma unroll
        for (int j = 0; j < 4; ++j) {
          int colc = wc * 64 + j * 16 + lm;
          float v = acc[i][j][r];
          if (RELU_BIAS) { v += bias[colc]; v = fmaxf(v, 0.f); }
          C[(size_t)row * 128 + colc] = f2bf(v);
        }
      }
    }
  }
}

// ---------------- attention logits (bf16 xh) ----------------
__global__ void att_logits_kernel(const ushort* __restrict__ xh,
                                  const float* __restrict__ att_s,
                                  const float* __restrict__ att_d,
                                  float* __restrict__ al_s, float* __restrict__ al_d, int n) {
  int t = blockIdx.x * blockDim.x + threadIdx.x;  // one per (node, head)
  if (t >= n * NHEAD) return;
  int head = t & 7;
  const unsigned* xw = (const unsigned*)(xh + (size_t)t * 16);
  const float* as = att_s + head * 16;
  const float* ad = att_d + head * 16;
  float ss = 0.f, dd = 0.f;
  #pragma unroll
  for (int i = 0; i < 8; ++i) {
    unsigned w = xw[i];
    float x0 = bflo(w), x1 = bfhi(w);
    ss = fmaf(x0, as[i * 2], fmaf(x1, as[i * 2 + 1], ss));
    dd = fmaf(x0, ad[i * 2], fmaf(x1, ad[i * 2 + 1], dd));
  }
  al_s[t] = ss;
  al_d[t] = dd;
}

// ---------------- GAT aggregation: 8-edge-parallel chunk-online softmax ----------------
__global__ __launch_bounds__(256) void gat_aggregate(
    const ushort* __restrict__ xh, const float* __restrict__ al_s,
    const float* __restrict__ al_d, const int* __restrict__ rowptr,
    const int* __restrict__ col, const ushort* __restrict__ h_res,
    const float* __restrict__ gb, const float* __restrict__ lng,
    const float* __restrict__ lnb, ushort* __restrict__ h_out, int n) {
  const int lane = threadIdx.x & 63;
  const int node = (blockIdx.x * blockDim.x + threadIdx.x) >> 6;
  if (node >= n) return;
  const int e8 = lane >> 3;     // compute mapping: edge-in-chunk
  const int hh = lane & 7;      // compute mapping: head
  const int head = lane >> 3;   // accumulate mapping: head
  const unsigned* xw_base = (const unsigned*)xh;

  const int start = rowptr[node], end = rowptr[node + 1];
  const int T = end - start + 1;              // + self-loop (item T-1)
  const float ald_c = al_d[node * 8 + hh];

  float m = -INFINITY, denom = 0.f, acc0 = 0.f, acc1 = 0.f;

  for (int c = 0; c < T; c += 8) {
    int it = c + e8;
    bool valid = it < T;
    int idx = start + it;
    int s = (valid && idx < end) ? col[idx] : node;
    float e = al_s[s * 8 + hh] + ald_c;
    e = (e > 0.f) ? e : 0.2f * e;
    if (!valid) e = -INFINITY;
    float cm = e;
    cm = fmaxf(cm, __shfl_xor(cm, 8));
    cm = fmaxf(cm, __shfl_xor(cm, 16));
    cm = fmaxf(cm, __shfl_xor(cm, 32));
    float newm = fmaxf(m, __shfl(cm, head));
    float newm_c = __shfl(newm, hh * 8);
    float p_lane = __expf(e - newm_c);
    float scale = __expf(m - newm);
    m = newm;
    unsigned xg[8];
    int sj[8];
    #pragma unroll
    for (int j = 0; j < 8; ++j) sj[j] = __shfl(s, j * 8);
    #pragma unroll
    for (int j = 0; j < 8; ++j) xg[j] = xw_base[(size_t)sj[j] * 64 + lane];
    denom *= scale; acc0 *= scale; acc1 *= scale;
    #pragma unroll
    for (int j = 0; j < 8; ++j) {
      float pj = __shfl(p_lane, j * 8 + head);
      denom += pj;
      acc0 = fmaf(pj, bflo(xg[j]), acc0);
      acc1 = fmaf(pj, bfhi(xg[j]), acc1);
    }
  }

  float inv = 1.f / denom;
  int c0 = lane * 2, c1 = c0 + 1;
  unsigned ur = ((const unsigned*)h_res)[(size_t)node * 64 + lane];
  float v0 = acc0 * inv + gb[c0] + bflo(ur);
  float v1 = acc1 * inv + gb[c1] + bfhi(ur);
  float sum = v0 + v1;
  #pragma unroll
  for (int off = 32; off; off >>= 1) sum += __shfl_xor(sum, off);
  float mean = sum * (1.f / 128.f);
  float d0 = v0 - mean, d1 = v1 - mean;
  float sq = d0 * d0 + d1 * d1;
  #pragma unroll
  for (int off = 32; off; off >>= 1) sq += __shfl_xor(sq, off);
  float rstd = rsqrtf(sq * (1.f / 128.f) + 1e-5f);
  float o0 = fmaxf(d0 * rstd * lng[c0] + lnb[c0], 0.f);
  float o1 = fmaxf(d1 * rstd * lng[c1] + lnb[c1], 0.f);
  ((unsigned*)h_out)[(size_t)node * 64 + lane] =
      (unsigned)f2bf(o0) | ((unsigned)f2bf(o1) << 16);
}

// ---------------- MFMA classifier (bf16 h in) ----------------
#define CSTR 136
#define HSTR 72
__global__ __launch_bounds__(256) void classifier_mfma(
    const ushort* __restrict__ h, const ushort* __restrict__ w1t,
    const float* __restrict__ b1, const ushort* __restrict__ w2t,
    const float* __restrict__ b2, float* __restrict__ out, int n) {
  __shared__ ushort sA[128 * CSTR];
  __shared__ ushort sB[64 * CSTR];
  __shared__ ushort sHid[128 * HSTR];
  const int tid = threadIdx.x;
  const int wave = tid >> 6, lane = tid & 63;
  const int q = lane >> 4, lm = lane & 15;
  const int wr = wave >> 1, wc = wave & 1;
  const int m0 = blockIdx.x * 128;

  #pragma unroll
  for (int p = 0; p < 8; ++p) {
    int idx = p * 256 + tid;
    int r = idx >> 4;
    int c = (idx & 15) << 3;
    int row = min(m0 + r, n - 1);
    *(bf16x8*)&sA[r * CSTR + c] = *(const bf16x8*)(h + (size_t)row * 128 + c);
  }
  #pragma unroll
  for (int p = 0; p < 4; ++p) {
    int idx = p * 256 + tid;
    int r = idx >> 4;
    int c = (idx & 15) << 3;
    *(bf16x8*)&sB[r * CSTR + c] = *(const bf16x8*)(w1t + r * 128 + c);
  }
  __syncthreads();

  f32x4 acc[4][2];
  #pragma unroll
  for (int i = 0; i < 4; ++i)
    #pragma unroll
    for (int j = 0; j < 2; ++j) acc[i][j] = {0.f, 0.f, 0.f, 0.f};
  #pragma unroll
  for (int ks = 0; ks < 4; ++ks) {
    bf16x8 af[4], bfv[2];
    #pragma unroll
    for (int t = 0; t < 4; ++t)
      af[t] = *(const bf16x8*)&sA[(wr * 64 + t * 16 + lm) * CSTR + ks * 32 + q * 8];
    #pragma unroll
    for (int j = 0; j < 2; ++j)
      bfv[j] = *(const bf16x8*)&sB[(wc * 32 + j * 16 + lm) * CSTR + ks * 32 + q * 8];
    #pragma unroll
    for (int i = 0; i < 4; ++i)
      #pragma unroll
      for (int j = 0; j < 2; ++j)
        acc[i][j] = __builtin_amdgcn_mfma_f32_16x16x32_bf16(af[i], bfv[j], acc[i][j], 0, 0, 0);
  }
  #pragma unroll
  for (int i = 0; i < 4; ++i) {
    #pragma unroll
    for (int j = 0; j < 2; ++j) {
      int colc = wc * 32 + j * 16 + lm;
      float bb = b1[colc];
      #pragma unroll
      for (int r = 0; r < 4; ++r) {
        int row = wr * 64 + i * 16 + q * 4 + r;
        float v = fmaxf(acc[i][j][r] + bb, 0.f);
        sHid[row * HSTR + colc] = f2bf(v);
      }
    }
  }
  __syncthreads();

  f32x4 acc2[2] = {{0.f, 0.f, 0.f, 0.f}, {0.f, 0.f, 0.f, 0.f}};
  #pragma unroll
  for (int ks = 0; ks < 2; ++ks) {
    bf16x8 b2f = *(const bf16x8*)(w2t + lm * 64 + ks * 32 + q * 8);
    #pragma unroll
    for (int t = 0; t < 2; ++t) {
      bf16x8 a2 = *(const bf16x8*)&sHid[(wave * 32 + t * 16 + lm) * HSTR + ks * 32 + q * 8];
      acc2[t] = __builtin_amdgcn_mfma_f32_16x16x32_bf16(a2, b2f, acc2[t], 0, 0, 0);
    }
  }
  float bb2 = b2[lm];
  #pragma unroll
  for (int t = 0; t < 2; ++t) {
    #pragma unroll
    for (int r = 0; r < 4; ++r) {
      int row = m0 + wave * 32 + t * 16 + q * 4 + r;
      float lg = acc2[t][r] + bb2;
      float mx = lg;
      #pragma unroll
      for (int off = 8; off; off >>= 1) mx = fmaxf(mx, __shfl_xor(mx, off, 16));
      float se = __expf(lg - mx);
      #pragma unroll
      for (int off = 8; off; off >>= 1) se += __shfl_xor(se, off, 16);
      if (row < n) out[(size_t)row * 16 + lm] = lg - mx - __logf(se);
    }
  }
}

// ---------------- launch ----------------
extern "C" void kernel_launch(void* const* d_in, const int* in_sizes, int n_in,
                              void* d_out, int out_size, void* d_ws, size_t ws_size,
                              hipStream_t stream) {
  const float* x       = (const float*)d_in[0];
  const int*   ei      = (const int*)d_in[1];
  const float* proj_w  = (const float*)d_in[2];
  const float* proj_b  = (const float*)d_in[3];
  const float* lin_w   = (const float*)d_in[4];
  const float* att_src = (const float*)d_in[5];
  const float* att_dst = (const float*)d_in[6];
  const float* gat_b   = (const float*)d_in[7];
  const float* ln_g    = (const float*)d_in[8];
  const float* ln_b    = (const float*)d_in[9];
  const float* cls_w1  = (const float*)d_in[10];
  const float* cls_b1  = (const float*)d_in[11];
  const float* cls_w2  = (const float*)d_in[12];
  const float* cls_b2  = (const float*)d_in[13];
  float* outp = (float*)d_out;

  const int N = NN, E = EE;
  ushort* wt   = (ushort*)d_ws;                     // 107520 used, reserve 108544
  ushort* h0   = wt + 108544;                       // N*128 bf16
  ushort* h1   = h0 + (size_t)N * 128;
  ushort* xh_u = h1 + (size_t)N * 128;
  float* als   = (float*)(xh_u + (size_t)N * 128);
  float* ald   = als + (size_t)N * NHEAD;
  int* counts  = (int*)(ald + (size_t)N * NHEAD);
  int* rowptr  = counts + N;
  int* woff    = rowptr + N + 1;
  int* col     = woff + N;
  int* bsum    = col + E;
  int* boff    = bsum + SCAN_NBLK;

  const int* e_src = ei;
  const int* e_dst = ei + E;

  prep_weights<<<(107520 + 255) / 256, 256, 0, stream>>>(proj_w, lin_w, cls_w1, cls_w2, wt);

  zero_ints<<<(N + 255) / 256, 256, 0, stream>>>(counts, N);
  hist_kernel<<<(E + 255) / 256, 256, 0, stream>>>(e_dst, counts, E);
  partial_sums<<<SCAN_NBLK, 256, 0, stream>>>(counts, bsum, N);
  scan_bsums<<<1, 256, 0, stream>>>(bsum, boff, SCAN_NBLK);
  final_scan<<<SCAN_NBLK, 256, 0, stream>>>(counts, boff, rowptr, woff, N);
  scatter_kernel<<<(E + 255) / 256, 256, 0, stream>>>(e_src, e_dst, woff, col, E);

  const int gblocks = (N + 63) / 64;  // 782 blocks: ~3/CU
  mfma_gemm64<float, true><<<gblocks, 256, 0, stream>>>(x, wt, proj_b, h0, N, DIN);

  ushort* hc = h0;
  ushort* hn = h1;
  for (int l = 0; l < 3; ++l) {
    mfma_gemm64<ushort, false><<<gblocks, 256, 0, stream>>>(
        hc, wt + 49152 + l * 16384, nullptr, xh_u, N, 128);
    att_logits_kernel<<<(N * NHEAD + 255) / 256, 256, 0, stream>>>(
        xh_u, att_src + l * 128, att_dst + l * 128, als, ald, N);
    gat_aggregate<<<(N + 3) / 4, 256, 0, stream>>>(
        xh_u, als, ald, rowptr, col, hc, gat_b + l * 128, ln_g + l * 128,
        ln_b + l * 128, hn, N);
    ushort* t = hc; hc = hn; hn = t;
  }
  classifier_mfma<<<(N + 127) / 128, 256, 0, stream>>>(
      hc, wt + 98304, cls_b1, wt + 106496, cls_b2, outp, N);
}